// Round 1
// baseline (1429.959 us; speedup 1.0000x reference)
//
#include <hip/hip_runtime.h>
#include <hip/hip_bf16.h>

// Problem constants (AttentionMIL): B=8 bags, N=50000 instances, D=256, H=128, C=2
#define B_   8
#define N_   50000
#define D_   256
#define H_   128
#define M_   (B_ * N_)          // 400000 rows
#define EPS_ 1e-5f
#define INV_TAU 3.33333333333333f   // 1/0.3

// Fused kernel tiling
#define RT 32                   // rows per block
#define XS_STR 260              // x tile row stride (256 + 4 pad, keeps float4 align, staggers banks)
#define HS_STR 132              // h tile row stride (128 + 4 pad)

__device__ __forceinline__ unsigned short f2bf(float f) {
    unsigned int u = __float_as_uint(f);
    unsigned int r = (u + 0x7FFFu + ((u >> 16) & 1u)) >> 16;   // RNE
    return (unsigned short)r;
}

__device__ __forceinline__ float fast_tanh(float x) {
    // tanh(x) = 1 - 2/(e^{2x}+1); saturates correctly for |x| large.
    return 1.0f - 2.0f * __fdividef(1.0f, __expf(2.0f * x) + 1.0f);
}

#define FMA4(r, xv) \
    acc[r][0] = fmaf(xv, wv.x, acc[r][0]); \
    acc[r][1] = fmaf(xv, wv.y, acc[r][1]); \
    acc[r][2] = fmaf(xv, wv.z, acc[r][2]); \
    acc[r][3] = fmaf(xv, wv.w, acc[r][3]);

// Kernel 1: per row, fused  h1 = relu(LN(x@W1+b1)); h2 = relu(LN(h1@W2+b2));
// score = tanh(h2@Wa1+ba1)@Wa2 + ba2.  Writes h2 (bf16) and score to ws.
// Block = 256 threads = 32 rows x 128 cols, micro-tile 4x4 per thread.
// Thread map: cid = tid&31 (cols cid*4..+3), rid = tid>>5 (rows rid*4..+3).
// Row r's 128 cols live in 32 contiguous lanes of one wave -> LN stats via
// __shfl_xor(16..1) with no LDS round trip.
__global__ __launch_bounds__(256, 2)
void k1_fused(const float* __restrict__ x,
              const float* __restrict__ W1, const float* __restrict__ b1,
              const float* __restrict__ g1, const float* __restrict__ be1,
              const float* __restrict__ W2, const float* __restrict__ b2,
              const float* __restrict__ g2, const float* __restrict__ be2,
              const float* __restrict__ Wa1, const float* __restrict__ ba1,
              const float* __restrict__ Wa2, const float* __restrict__ ba2,
              unsigned short* __restrict__ h2g, float* __restrict__ scores)
{
    __shared__ float smem[RT * XS_STR];   // x tile; reused as h2 tile after layer 2
    __shared__ float h1s[RT * HS_STR];    // h1 tile

    const int tid  = threadIdx.x;
    const int cid  = tid & 31;
    const int rid  = tid >> 5;
    const int row0 = rid * 4;
    const int col0 = cid * 4;
    const size_t base = (size_t)blockIdx.x * RT;

    // ---- stage x tile (32 x 256) into LDS, coalesced float4 ----
    {
        const float4* xg = (const float4*)(x + base * D_);
        #pragma unroll
        for (int it = 0; it < 8; ++it) {
            int i4 = it * 256 + tid;          // [0, 2048): 32 rows x 64 float4
            int r  = i4 >> 6;
            int c4 = i4 & 63;
            float4 v = xg[i4];
            *(float4*)(smem + r * XS_STR + c4 * 4) = v;
        }
    }
    __syncthreads();

    float acc[4][4];

    // ================= layer 1 GEMM: y = x @ W1 =================
    #pragma unroll
    for (int r = 0; r < 4; ++r)
        #pragma unroll
        for (int c = 0; c < 4; ++c) acc[r][c] = 0.f;

    {
        const float* xr0 = smem + (row0 + 0) * XS_STR;
        const float* xr1 = smem + (row0 + 1) * XS_STR;
        const float* xr2 = smem + (row0 + 2) * XS_STR;
        const float* xr3 = smem + (row0 + 3) * XS_STR;
        #pragma unroll 4
        for (int k = 0; k < D_; ++k) {
            float4 wv = *(const float4*)(W1 + (size_t)k * H_ + col0);
            float x0 = xr0[k], x1 = xr1[k], x2 = xr2[k], x3 = xr3[k];
            FMA4(0, x0) FMA4(1, x1) FMA4(2, x2) FMA4(3, x3)
        }
    }

    // ---- LN1 + ReLU -> h1s ----
    {
        float4 bv = *(const float4*)(b1  + col0);
        float4 gv = *(const float4*)(g1  + col0);
        float4 ev = *(const float4*)(be1 + col0);
        #pragma unroll
        for (int r = 0; r < 4; ++r) {
            float a0 = acc[r][0] + bv.x;
            float a1 = acc[r][1] + bv.y;
            float a2 = acc[r][2] + bv.z;
            float a3 = acc[r][3] + bv.w;
            float s  = a0 + a1 + a2 + a3;
            float s2 = a0*a0 + a1*a1 + a2*a2 + a3*a3;
            #pragma unroll
            for (int o = 16; o; o >>= 1) {
                s  += __shfl_xor(s,  o);
                s2 += __shfl_xor(s2, o);
            }
            float mu  = s  * (1.f / H_);
            float var = s2 * (1.f / H_) - mu * mu;
            float rs  = rsqrtf(var + EPS_);
            float4 h;
            h.x = fmaxf(fmaf((a0 - mu) * rs, gv.x, ev.x), 0.f);
            h.y = fmaxf(fmaf((a1 - mu) * rs, gv.y, ev.y), 0.f);
            h.z = fmaxf(fmaf((a2 - mu) * rs, gv.z, ev.z), 0.f);
            h.w = fmaxf(fmaf((a3 - mu) * rs, gv.w, ev.w), 0.f);
            *(float4*)(h1s + (row0 + r) * HS_STR + col0) = h;
        }
    }
    __syncthreads();

    // ================= layer 2 GEMM: y = h1 @ W2 =================
    #pragma unroll
    for (int r = 0; r < 4; ++r)
        #pragma unroll
        for (int c = 0; c < 4; ++c) acc[r][c] = 0.f;
    {
        const float* hr0 = h1s + (row0 + 0) * HS_STR;
        const float* hr1 = h1s + (row0 + 1) * HS_STR;
        const float* hr2 = h1s + (row0 + 2) * HS_STR;
        const float* hr3 = h1s + (row0 + 3) * HS_STR;
        #pragma unroll 4
        for (int k = 0; k < H_; ++k) {
            float4 wv = *(const float4*)(W2 + (size_t)k * H_ + col0);
            float x0 = hr0[k], x1 = hr1[k], x2 = hr2[k], x3 = hr3[k];
            FMA4(0, x0) FMA4(1, x1) FMA4(2, x2) FMA4(3, x3)
        }
    }

    // ---- LN2 + ReLU -> smem (h2 tile) + global bf16 h2 ----
    {
        float4 bv = *(const float4*)(b2  + col0);
        float4 gv = *(const float4*)(g2  + col0);
        float4 ev = *(const float4*)(be2 + col0);
        #pragma unroll
        for (int r = 0; r < 4; ++r) {
            float a0 = acc[r][0] + bv.x;
            float a1 = acc[r][1] + bv.y;
            float a2 = acc[r][2] + bv.z;
            float a3 = acc[r][3] + bv.w;
            float s  = a0 + a1 + a2 + a3;
            float s2 = a0*a0 + a1*a1 + a2*a2 + a3*a3;
            #pragma unroll
            for (int o = 16; o; o >>= 1) {
                s  += __shfl_xor(s,  o);
                s2 += __shfl_xor(s2, o);
            }
            float mu  = s  * (1.f / H_);
            float var = s2 * (1.f / H_) - mu * mu;
            float rs  = rsqrtf(var + EPS_);
            float4 h;
            h.x = fmaxf(fmaf((a0 - mu) * rs, gv.x, ev.x), 0.f);
            h.y = fmaxf(fmaf((a1 - mu) * rs, gv.y, ev.y), 0.f);
            h.z = fmaxf(fmaf((a2 - mu) * rs, gv.z, ev.z), 0.f);
            h.w = fmaxf(fmaf((a3 - mu) * rs, gv.w, ev.w), 0.f);
            *(float4*)(smem + (row0 + r) * HS_STR + col0) = h;
            ushort4 p;
            p.x = f2bf(h.x); p.y = f2bf(h.y); p.z = f2bf(h.z); p.w = f2bf(h.w);
            *(ushort4*)(h2g + (base + row0 + r) * H_ + col0) = p;
        }
    }
    __syncthreads();

    // ================= attention GEMM: t = tanh(h2 @ Wa1 + ba1); score = t.Wa2 + ba2 ====
    #pragma unroll
    for (int r = 0; r < 4; ++r)
        #pragma unroll
        for (int c = 0; c < 4; ++c) acc[r][c] = 0.f;
    {
        const float* hr0 = smem + (row0 + 0) * HS_STR;
        const float* hr1 = smem + (row0 + 1) * HS_STR;
        const float* hr2 = smem + (row0 + 2) * HS_STR;
        const float* hr3 = smem + (row0 + 3) * HS_STR;
        #pragma unroll 4
        for (int k = 0; k < H_; ++k) {
            float4 wv = *(const float4*)(Wa1 + (size_t)k * H_ + col0);
            float x0 = hr0[k], x1 = hr1[k], x2 = hr2[k], x3 = hr3[k];
            FMA4(0, x0) FMA4(1, x1) FMA4(2, x2) FMA4(3, x3)
        }
    }
    {
        float4 bv = *(const float4*)(ba1 + col0);
        float4 wv = *(const float4*)(Wa2 + col0);
        const float ba2s = ba2[0];
        float local[4];
        #pragma unroll
        for (int r = 0; r < 4; ++r) {
            float t0 = fast_tanh(acc[r][0] + bv.x);
            float t1 = fast_tanh(acc[r][1] + bv.y);
            float t2 = fast_tanh(acc[r][2] + bv.z);
            float t3 = fast_tanh(acc[r][3] + bv.w);
            local[r] = t0*wv.x + t1*wv.y + t2*wv.z + t3*wv.w;
        }
        #pragma unroll
        for (int o = 16; o; o >>= 1) {
            local[0] += __shfl_xor(local[0], o);
            local[1] += __shfl_xor(local[1], o);
            local[2] += __shfl_xor(local[2], o);
            local[3] += __shfl_xor(local[3], o);
        }
        if (cid == 0) {
            #pragma unroll
            for (int r = 0; r < 4; ++r)
                scores[base + row0 + r] = local[r] + ba2s;
        }
    }
}

// Kernel 2: per-bag softmax stats (max, sum of exp) + zero the bag accumulator.
__global__ __launch_bounds__(1024)
void k2_stats(const float* __restrict__ scores, float* __restrict__ mz,
              float* __restrict__ bag)
{
    const int b   = blockIdx.x;
    const int tid = threadIdx.x;
    __shared__ float red[17];

    if (tid < H_) bag[b * H_ + tid] = 0.f;

    const float* s = scores + (size_t)b * N_;
    float m = -1e30f;
    for (int n = tid; n < N_; n += 1024) m = fmaxf(m, s[n]);
    #pragma unroll
    for (int o = 32; o; o >>= 1) m = fmaxf(m, __shfl_xor(m, o));
    if ((tid & 63) == 0) red[tid >> 6] = m;
    __syncthreads();
    if (tid == 0) {
        float v = red[0];
        for (int i = 1; i < 16; ++i) v = fmaxf(v, red[i]);
        red[16] = v;
    }
    __syncthreads();
    const float mb = red[16];
    __syncthreads();

    float z = 0.f;
    for (int n = tid; n < N_; n += 1024) z += __expf((s[n] - mb) * INV_TAU);
    #pragma unroll
    for (int o = 32; o; o >>= 1) z += __shfl_xor(z, o);
    if ((tid & 63) == 0) red[tid >> 6] = z;
    __syncthreads();
    if (tid == 0) {
        float v = 0.f;
        for (int i = 0; i < 16; ++i) v += red[i];
        mz[b * 2]     = mb;
        mz[b * 2 + 1] = v;
    }
}

// Kernel 3: attention-weighted pooling  bag[b][j] = sum_n attn(b,n) * h2[b,n,j].
// Grid = B * 128 chunks; block 256 threads: jp = tid&63 handles j-pair, nof = tid>>6.
#define CHUNKS_ 128
#define CHN_ 391   // ceil(50000/128)
__global__ __launch_bounds__(256)
void k3_pool(const unsigned short* __restrict__ h2,
             const float* __restrict__ scores,
             const float* __restrict__ mz,
             float* __restrict__ bag)
{
    const int b   = blockIdx.x / CHUNKS_;
    const int ch  = blockIdx.x % CHUNKS_;
    const int tid = threadIdx.x;
    const int jp  = tid & 63;      // pair of feature channels
    const int nof = tid >> 6;      // 0..3

    const int n0 = ch * CHN_;
    const int n1 = (n0 + CHN_ < N_) ? (n0 + CHN_) : N_;

    const float  m    = mz[b * 2];
    const float  invZ = __fdividef(1.f, mz[b * 2 + 1]);
    const float* s    = scores + (size_t)b * N_;

    float accx = 0.f, accy = 0.f;
    for (int n = n0 + nof; n < n1; n += 4) {
        float w = __expf((s[n] - m) * INV_TAU) * invZ;
        unsigned pv = *(const unsigned*)(h2 + ((size_t)b * N_ + n) * H_ + jp * 2);
        float h0 = __uint_as_float(pv << 16);
        float h1 = __uint_as_float(pv & 0xFFFF0000u);
        accx = fmaf(w, h0, accx);
        accy = fmaf(w, h1, accy);
    }
    atomicAdd(&bag[b * H_ + jp * 2],     accx);
    atomicAdd(&bag[b * H_ + jp * 2 + 1], accy);
}

// Kernel 4: tiny heads. 1 block, 128 threads.
__global__ __launch_bounds__(128)
void k4_heads(const float* __restrict__ bag,
              const float* __restrict__ Wc1, const float* __restrict__ bc1,
              const float* __restrict__ Wc2, const float* __restrict__ bc2,
              const float* __restrict__ Ws1, const float* __restrict__ bs1,
              const float* __restrict__ Ws2, const float* __restrict__ bs2,
              float* __restrict__ out)
{
    __shared__ float bl[B_ * H_];
    __shared__ float ul[B_ * H_];
    __shared__ float vl[B_ * 64];
    const int j = threadIdx.x;

    #pragma unroll
    for (int b = 0; b < B_; ++b) bl[b * H_ + j] = bag[b * H_ + j];
    __syncthreads();

    #pragma unroll
    for (int b = 0; b < B_; ++b) {
        float a = bc1[j];
        for (int k = 0; k < H_; ++k) a = fmaf(bl[b * H_ + k], Wc1[k * H_ + j], a);
        ul[b * H_ + j] = fmaxf(a, 0.f);
    }
    if (j < 64) {
        #pragma unroll
        for (int b = 0; b < B_; ++b) {
            float a = bs1[j];
            for (int k = 0; k < H_; ++k) a = fmaf(bl[b * H_ + k], Ws1[k * 64 + j], a);
            vl[b * 64 + j] = fmaxf(a, 0.f);
        }
    }
    __syncthreads();

    if (j < 16) {                       // logits [8][2]
        int b = j >> 1, c = j & 1;
        float a = bc2[c];
        for (int k = 0; k < H_; ++k) a = fmaf(ul[b * H_ + k], Wc2[k * 2 + c], a);
        out[b * 2 + c] = a;
    }
    if (j >= 32 && j < 40) {            // risk [8]
        int b = j - 32;
        float a = bs2[0];
        for (int k = 0; k < 64; ++k) a = fmaf(vl[b * 64 + k], Ws2[k], a);
        out[16 + b] = a;
    }
}

extern "C" void kernel_launch(void* const* d_in, const int* in_sizes, int n_in,
                              void* d_out, int out_size, void* d_ws, size_t ws_size,
                              hipStream_t stream)
{
    (void)in_sizes; (void)n_in; (void)out_size; (void)ws_size;

    const float* x   = (const float*)d_in[0];
    const float* W1  = (const float*)d_in[1];
    const float* b1  = (const float*)d_in[2];
    const float* g1  = (const float*)d_in[3];
    const float* be1 = (const float*)d_in[4];
    const float* W2  = (const float*)d_in[5];
    const float* b2  = (const float*)d_in[6];
    const float* g2  = (const float*)d_in[7];
    const float* be2 = (const float*)d_in[8];
    const float* Wa1 = (const float*)d_in[9];
    const float* ba1 = (const float*)d_in[10];
    const float* Wa2 = (const float*)d_in[11];
    const float* ba2 = (const float*)d_in[12];
    const float* Wc1 = (const float*)d_in[13];
    const float* bc1 = (const float*)d_in[14];
    const float* Wc2 = (const float*)d_in[15];
    const float* bc2 = (const float*)d_in[16];
    const float* Ws1 = (const float*)d_in[17];
    const float* bs1 = (const float*)d_in[18];
    const float* Ws2 = (const float*)d_in[19];
    const float* bs2 = (const float*)d_in[20];

    // workspace layout
    char* ws = (char*)d_ws;
    unsigned short* h2 = (unsigned short*)ws;                        // 400000*128*2 = 102,400,000 B
    float* scores      = (float*)(ws + 102400000);                   // 1,600,000 B
    float* mz          = (float*)(ws + 104000000);                   // 64 B
    float* bag         = (float*)(ws + 104000128);                   // 4096 B

    k1_fused<<<M_ / RT, 256, 0, stream>>>(x, W1, b1, g1, be1, W2, b2, g2, be2,
                                          Wa1, ba1, Wa2, ba2, h2, scores);
    k2_stats<<<B_, 1024, 0, stream>>>(scores, mz, bag);
    k3_pool<<<B_ * CHUNKS_, 256, 0, stream>>>(h2, scores, mz, bag);
    k4_heads<<<1, 128, 0, stream>>>(bag, Wc1, bc1, Wc2, bc2, Ws1, bs1, Ws2, bs2,
                                    (float*)d_out);
}

// Round 2
// 853.007 us; speedup vs baseline: 1.6764x; 1.6764x over previous
//
#include <hip/hip_runtime.h>

// AttentionMIL: B=8 bags, N=50000 instances, D=256, H=128, C=2
#define B_   8
#define N_   50000
#define D_   256
#define H_   128
#define M_   (B_ * N_)          // 400000 rows
#define EPS_ 1e-5f
#define INV_TAU 3.33333333f     // 1/0.3

#define RB   128                // rows per block (4 waves x 32)
#define HSTR 136                // htile row stride in bf16 elems (128 + 8: keeps 16B align, breaks bank stride)
#define NBLK (M_ / RB)          // 3125 blocks

typedef __attribute__((ext_vector_type(8))) short bf16x8;   // 8 bf16 = 4 VGPRs (MFMA A/B frag)
typedef __attribute__((ext_vector_type(4))) float f32x4;    // MFMA C/D frag

union UB { bf16x8 v; unsigned short u[8]; };
union F8 { float4 f4[2]; float f[8]; };

__device__ __forceinline__ unsigned short f2bf(float f) {   // fp32 -> bf16 RNE
    unsigned int u = __float_as_uint(f);
    return (unsigned short)((u + 0x7FFFu + ((u >> 16) & 1u)) >> 16);
}
__device__ __forceinline__ float bf2f(unsigned short s) {
    return __uint_as_float(((unsigned int)s) << 16);
}
__device__ __forceinline__ float fast_tanh(float x) {
    return 1.0f - 2.0f * __fdividef(1.0f, __expf(2.0f * x) + 1.0f);
}

// ---------------------------------------------------------------------------
// k0: repack W1/W2/Wa1 (fp32 [K][128] row-major) into bf16 MFMA-B-frag layout:
//   Wp[((kc*8 + nt)*64 + lane)*8 + j] = bf16(W[kc*32 + (lane>>4)*8 + j][nt*16 + (lane&15)])
// so a lane's B fragment for tile (kc,nt) is one contiguous 16B load.
// 8192 threads total (W1: 4096, W2: 2048, Wa1: 2048).
// ---------------------------------------------------------------------------
__global__ __launch_bounds__(256)
void k0_pack(const float* __restrict__ W1, const float* __restrict__ W2,
             const float* __restrict__ Wa1,
             unsigned short* __restrict__ W1p, unsigned short* __restrict__ W2p,
             unsigned short* __restrict__ Wa1p)
{
    int t = blockIdx.x * 256 + threadIdx.x;
    const float* src; unsigned short* dst; int idx;
    if (t < 4096)      { src = W1;  dst = W1p;  idx = t; }
    else if (t < 6144) { src = W2;  dst = W2p;  idx = t - 4096; }
    else               { src = Wa1; dst = Wa1p; idx = t - 6144; }
    int l   = idx & 63;
    int nt  = (idx >> 6) & 7;
    int kc  = idx >> 9;
    int col = nt * 16 + (l & 15);
    int kb  = kc * 32 + (l >> 4) * 8;
    UB o;
    #pragma unroll
    for (int j = 0; j < 8; ++j) o.u[j] = f2bf(src[(size_t)(kb + j) * H_ + col]);
    *(bf16x8*)(dst + (size_t)idx * 8) = o.v;
}

// LN(+bias) + ReLU on MFMA C/D-layout accumulators, store bf16 to htile.
// C/D layout (16x16x32): col = lane&15, row = (lane>>4)*4 + reg  [m89/m91].
// LN is over the 128 cols = reduce across the 16-lane column group: shfl_xor 1,2,4,8.
__device__ __forceinline__ void ln_relu_store(
    f32x4 (&acc)[2][8],
    const float* __restrict__ bb, const float* __restrict__ gg, const float* __restrict__ ee,
    unsigned short* __restrict__ htile, int wrow0, int n16, int kq)
{
    float bc[8], gc[8], ec[8];
    #pragma unroll
    for (int nt = 0; nt < 8; ++nt) {
        int col = nt * 16 + n16;
        bc[nt] = bb[col]; gc[nt] = gg[col]; ec[nt] = ee[col];
    }
    #pragma unroll
    for (int m = 0; m < 2; ++m) {
        #pragma unroll
        for (int r = 0; r < 4; ++r) {
            float v[8];
            float s = 0.f, s2 = 0.f;
            #pragma unroll
            for (int nt = 0; nt < 8; ++nt) {
                float t = acc[m][nt][r] + bc[nt];
                v[nt] = t; s += t; s2 = fmaf(t, t, s2);
            }
            #pragma unroll
            for (int o = 1; o <= 8; o <<= 1) {
                s  += __shfl_xor(s,  o);
                s2 += __shfl_xor(s2, o);
            }
            float mu  = s * (1.f / H_);
            float var = s2 * (1.f / H_) - mu * mu;
            float rs  = rsqrtf(var + EPS_);
            int row = wrow0 + m * 16 + kq * 4 + r;
            #pragma unroll
            for (int nt = 0; nt < 8; ++nt) {
                float h = fmaxf(fmaf((v[nt] - mu) * rs, gc[nt], ec[nt]), 0.f);
                htile[row * HSTR + nt * 16 + n16] = f2bf(h);
            }
        }
    }
}

// ---------------------------------------------------------------------------
// k1: per 128-row block, fully fused:
//   h1 = relu(LN(x@W1+b1)); h2 = relu(LN(h1@W2+b2));
//   w  = exp((tanh(h2@Wa1+ba1)@Wa2 + ba2)/tau)      (no max-sub: |score|<=11.4 -> exp<=e^38, fp32-safe)
//   per-block partials: Z_s = sum w, pooled_s[j] = sum w*h2[:,j]   (s = bag slot, 2 per block)
// MFMA 16x16x32 bf16; A frags: lane holds A[m=lane&15][k=(lane>>4)*8+j] (m120).
// htile rows are wave-private until the pooling barrier -> no inter-layer syncs.
// ---------------------------------------------------------------------------
__global__ __launch_bounds__(256, 2)
void k1_mfma(const float* __restrict__ x,
             const unsigned short* __restrict__ W1p,
             const unsigned short* __restrict__ W2p,
             const unsigned short* __restrict__ Wa1p,
             const float* __restrict__ b1, const float* __restrict__ g1, const float* __restrict__ be1,
             const float* __restrict__ b2, const float* __restrict__ g2, const float* __restrict__ be2,
             const float* __restrict__ ba1, const float* __restrict__ Wa2, const float* __restrict__ ba2,
             float* __restrict__ Zarr, float* __restrict__ Pool)
{
    __shared__ __align__(16) unsigned short htile[RB * HSTR];   // 34 KB
    __shared__ float swarr[RB];
    __shared__ float parr[2][2][H_];                            // 4 KB

    const int tid   = threadIdx.x;
    const int w     = tid >> 6;
    const int l     = tid & 63;
    const int n16   = l & 15;
    const int kq    = l >> 4;
    const int base  = blockIdx.x * RB;
    const int wrow0 = w * 32;

    f32x4 acc[2][8];

    // ================= layer 1: x(256) @ W1 -> 128, A from global =================
    #pragma unroll
    for (int m = 0; m < 2; ++m)
        #pragma unroll
        for (int nt = 0; nt < 8; ++nt) acc[m][nt] = f32x4{0.f, 0.f, 0.f, 0.f};

    for (int kc = 0; kc < 8; ++kc) {
        UB a[2];
        #pragma unroll
        for (int m = 0; m < 2; ++m) {
            const float* xp = x + (size_t)(base + wrow0 + m * 16 + n16) * D_ + kc * 32 + kq * 8;
            F8 xa;
            xa.f4[0] = *(const float4*)xp;
            xa.f4[1] = *(const float4*)(xp + 4);
            #pragma unroll
            for (int j = 0; j < 8; ++j) a[m].u[j] = f2bf(xa.f[j]);
        }
        const bf16x8* bp = (const bf16x8*)W1p + (size_t)kc * 8 * 64 + l;
        #pragma unroll
        for (int nt = 0; nt < 8; ++nt) {
            bf16x8 bv = bp[nt * 64];
            acc[0][nt] = __builtin_amdgcn_mfma_f32_16x16x32_bf16(a[0].v, bv, acc[0][nt], 0, 0, 0);
            acc[1][nt] = __builtin_amdgcn_mfma_f32_16x16x32_bf16(a[1].v, bv, acc[1][nt], 0, 0, 0);
        }
    }
    ln_relu_store(acc, b1, g1, be1, htile, wrow0, n16, kq);

    // ================= layer 2: h1(128) @ W2 -> 128, A from htile =================
    #pragma unroll
    for (int m = 0; m < 2; ++m)
        #pragma unroll
        for (int nt = 0; nt < 8; ++nt) acc[m][nt] = f32x4{0.f, 0.f, 0.f, 0.f};

    for (int kc = 0; kc < 4; ++kc) {
        bf16x8 a[2];
        #pragma unroll
        for (int m = 0; m < 2; ++m)
            a[m] = *(const bf16x8*)&htile[(wrow0 + m * 16 + n16) * HSTR + kc * 32 + kq * 8];
        const bf16x8* bp = (const bf16x8*)W2p + (size_t)kc * 8 * 64 + l;
        #pragma unroll
        for (int nt = 0; nt < 8; ++nt) {
            bf16x8 bv = bp[nt * 64];
            acc[0][nt] = __builtin_amdgcn_mfma_f32_16x16x32_bf16(a[0], bv, acc[0][nt], 0, 0, 0);
            acc[1][nt] = __builtin_amdgcn_mfma_f32_16x16x32_bf16(a[1], bv, acc[1][nt], 0, 0, 0);
        }
    }
    ln_relu_store(acc, b2, g2, be2, htile, wrow0, n16, kq);   // h2 overwrites h1 (wave-private rows)

    // ================= attention: tanh(h2 @ Wa1 + ba1) . Wa2 + ba2 =================
    #pragma unroll
    for (int m = 0; m < 2; ++m)
        #pragma unroll
        for (int nt = 0; nt < 8; ++nt) acc[m][nt] = f32x4{0.f, 0.f, 0.f, 0.f};

    for (int kc = 0; kc < 4; ++kc) {
        bf16x8 a[2];
        #pragma unroll
        for (int m = 0; m < 2; ++m)
            a[m] = *(const bf16x8*)&htile[(wrow0 + m * 16 + n16) * HSTR + kc * 32 + kq * 8];
        const bf16x8* bp = (const bf16x8*)Wa1p + (size_t)kc * 8 * 64 + l;
        #pragma unroll
        for (int nt = 0; nt < 8; ++nt) {
            bf16x8 bv = bp[nt * 64];
            acc[0][nt] = __builtin_amdgcn_mfma_f32_16x16x32_bf16(a[0], bv, acc[0][nt], 0, 0, 0);
            acc[1][nt] = __builtin_amdgcn_mfma_f32_16x16x32_bf16(a[1], bv, acc[1][nt], 0, 0, 0);
        }
    }
    {
        float bc[8], wc[8];
        #pragma unroll
        for (int nt = 0; nt < 8; ++nt) {
            int col = nt * 16 + n16;
            bc[nt] = ba1[col]; wc[nt] = Wa2[col];
        }
        const float ba2s = ba2[0];
        #pragma unroll
        for (int m = 0; m < 2; ++m) {
            #pragma unroll
            for (int r = 0; r < 4; ++r) {
                float p = 0.f;
                #pragma unroll
                for (int nt = 0; nt < 8; ++nt)
                    p = fmaf(fast_tanh(acc[m][nt][r] + bc[nt]), wc[nt], p);
                #pragma unroll
                for (int o = 1; o <= 8; o <<= 1) p += __shfl_xor(p, o);
                if (n16 == 0)
                    swarr[wrow0 + m * 16 + kq * 4 + r] = __expf((p + ba2s) * INV_TAU);
            }
        }
    }
    __syncthreads();

    // ================= block-local softmax partials + pooling =================
    const int bag0   = base / N_;
    int rsplit = (bag0 + 1) * N_ - base;        // rows < rsplit -> bag0 (slot 0); >= -> bag0+1 (slot 1)
    if (rsplit > RB) rsplit = RB;

    {
        const int j = tid & 127, half = tid >> 7;
        float a0 = 0.f, a1 = 0.f;
        for (int rr = 0; rr < 64; ++rr) {
            int row  = half * 64 + rr;
            float wv = swarr[row];
            float v  = wv * bf2f(htile[row * HSTR + j]);
            if (row < rsplit) a0 += v; else a1 += v;
        }
        parr[half][0][j] = a0;
        parr[half][1][j] = a1;
    }
    __syncthreads();
    if (tid < H_) {
        Pool[((size_t)blockIdx.x * 2 + 0) * H_ + tid] = parr[0][0][tid] + parr[1][0][tid];
        Pool[((size_t)blockIdx.x * 2 + 1) * H_ + tid] = parr[0][1][tid] + parr[1][1][tid];
    }
    if (tid >= 128 && tid < 192) {              // one full wave does the Z reductions
        int t = tid - 128;
        float wa = swarr[t], wb = swarr[t + 64];
        float z0 = (t < rsplit ? wa : 0.f) + (t + 64 < rsplit ? wb : 0.f);
        float z1 = (t >= rsplit ? wa : 0.f) + (t + 64 >= rsplit ? wb : 0.f);
        #pragma unroll
        for (int o = 1; o <= 32; o <<= 1) {
            z0 += __shfl_xor(z0, o);
            z1 += __shfl_xor(z1, o);
        }
        if (t == 0) {
            Zarr[blockIdx.x * 2 + 0] = z0;
            Zarr[blockIdx.x * 2 + 1] = z1;
        }
    }
}

// ---------------------------------------------------------------------------
// k2: per bag, merge block partials (bag = sum pooled / sum Z) + both heads.
// 8 blocks x 128 threads.
// ---------------------------------------------------------------------------
__global__ __launch_bounds__(128)
void k2_combine(const float* __restrict__ Zarr, const float* __restrict__ Pool,
                const float* __restrict__ Wc1, const float* __restrict__ bc1,
                const float* __restrict__ Wc2, const float* __restrict__ bc2,
                const float* __restrict__ Ws1, const float* __restrict__ bs1,
                const float* __restrict__ Ws2, const float* __restrict__ bs2,
                float* __restrict__ out)
{
    const int b = blockIdx.x, j = threadIdx.x;
    __shared__ float bl[H_], ul[H_], vl[64];

    const int blk0 = (b * N_) / RB;
    const int blk1 = ((b + 1) * N_ - 1) / RB;
    float ps = 0.f, zs = 0.f;
    for (int blk = blk0; blk <= blk1; ++blk) {
        int bag0 = (blk * RB) / N_;
        if (bag0 == b)     { ps += Pool[((size_t)blk * 2 + 0) * H_ + j]; zs += Zarr[blk * 2 + 0]; }
        if (bag0 + 1 == b) { ps += Pool[((size_t)blk * 2 + 1) * H_ + j]; zs += Zarr[blk * 2 + 1]; }
    }
    bl[j] = ps / zs;
    __syncthreads();

    float a = bc1[j];
    for (int k = 0; k < H_; ++k) a = fmaf(bl[k], Wc1[k * H_ + j], a);
    ul[j] = fmaxf(a, 0.f);
    if (j < 64) {
        float a2 = bs1[j];
        for (int k = 0; k < H_; ++k) a2 = fmaf(bl[k], Ws1[k * 64 + j], a2);
        vl[j] = fmaxf(a2, 0.f);
    }
    __syncthreads();

    if (j < 2) {
        float a3 = bc2[j];
        for (int k = 0; k < H_; ++k) a3 = fmaf(ul[k], Wc2[k * 2 + j], a3);
        out[b * 2 + j] = a3;
    }
    if (j == 2) {
        float a4 = bs2[0];
        for (int k = 0; k < 64; ++k) a4 = fmaf(vl[k], Ws2[k], a4);
        out[16 + b] = a4;
    }
}

extern "C" void kernel_launch(void* const* d_in, const int* in_sizes, int n_in,
                              void* d_out, int out_size, void* d_ws, size_t ws_size,
                              hipStream_t stream)
{
    (void)in_sizes; (void)n_in; (void)out_size; (void)ws_size;

    const float* x   = (const float*)d_in[0];
    const float* W1  = (const float*)d_in[1];
    const float* b1  = (const float*)d_in[2];
    const float* g1  = (const float*)d_in[3];
    const float* be1 = (const float*)d_in[4];
    const float* W2  = (const float*)d_in[5];
    const float* b2  = (const float*)d_in[6];
    const float* g2  = (const float*)d_in[7];
    const float* be2 = (const float*)d_in[8];
    const float* Wa1 = (const float*)d_in[9];
    const float* ba1 = (const float*)d_in[10];
    const float* Wa2 = (const float*)d_in[11];
    const float* ba2 = (const float*)d_in[12];
    const float* Wc1 = (const float*)d_in[13];
    const float* bc1 = (const float*)d_in[14];
    const float* Wc2 = (const float*)d_in[15];
    const float* bc2 = (const float*)d_in[16];
    const float* Ws1 = (const float*)d_in[17];
    const float* bs1 = (const float*)d_in[18];
    const float* Ws2 = (const float*)d_in[19];
    const float* bs2 = (const float*)d_in[20];

    // workspace layout (16B-aligned segments)
    char* ws = (char*)d_ws;
    float* Zarr          = (float*)ws;                       // 3125*2*4      = 25,000 B
    float* Pool          = (float*)(ws + 25088);             // 3125*2*128*4  = 3,200,000 B
    unsigned short* W1p  = (unsigned short*)(ws + 3225088);  // 64 KB
    unsigned short* W2p  = (unsigned short*)(ws + 3290624);  // 32 KB
    unsigned short* Wa1p = (unsigned short*)(ws + 3323392);  // 32 KB

    k0_pack<<<32, 256, 0, stream>>>(W1, W2, Wa1, W1p, W2p, Wa1p);
    k1_mfma<<<NBLK, 256, 0, stream>>>(x, W1p, W2p, Wa1p,
                                      b1, g1, be1, b2, g2, be2,
                                      ba1, Wa2, ba2, Zarr, Pool);
    k2_combine<<<B_, 128, 0, stream>>>(Zarr, Pool, Wc1, bc1, Wc2, bc2,
                                       Ws1, bs1, Ws2, bs2, (float*)d_out);
}

// Round 3
// 780.180 us; speedup vs baseline: 1.8329x; 1.0933x over previous
//
#include <hip/hip_runtime.h>

// AttentionMIL: B=8 bags, N=50000 instances, D=256, H=128, C=2
#define B_   8
#define N_   50000
#define D_   256
#define H_   128
#define M_   (B_ * N_)          // 400000 rows
#define EPS_ 1e-5f
#define INV_TAU 3.33333333f     // 1/0.3

#define RB   128                // rows per block (4 waves x 32)
#define HSTR 136                // htile row stride in bf16 elems (128+8: 16B-aligned rows, 2-way-max banks)
#define NBLK (M_ / RB)          // 3125 blocks

typedef __attribute__((ext_vector_type(8))) short bf16x8;   // 8 bf16 = 4 VGPRs (MFMA A/B frag)
typedef __attribute__((ext_vector_type(4))) float f32x4;    // MFMA C/D frag

union UB { bf16x8 v; unsigned short u[8]; };
union F8 { float4 f4[2]; float f[8]; };

__device__ __forceinline__ unsigned short f2bf(float f) {   // fp32 -> bf16 RNE
    unsigned int u = __float_as_uint(f);
    return (unsigned short)((u + 0x7FFFu + ((u >> 16) & 1u)) >> 16);
}
__device__ __forceinline__ float fast_tanh(float x) {
    return 1.0f - 2.0f * __fdividef(1.0f, __expf(2.0f * x) + 1.0f);
}

// ---------------------------------------------------------------------------
// k0: repack W1/W2/Wa1 (fp32 [K][128] row-major) into bf16 MFMA-B-frag layout:
//   Wp[((kc*8 + nt)*64 + lane)*8 + j] = bf16(W[kc*32 + (lane>>4)*8 + j][nt*16 + (lane&15)])
// ---------------------------------------------------------------------------
__global__ __launch_bounds__(256)
void k0_pack(const float* __restrict__ W1, const float* __restrict__ W2,
             const float* __restrict__ Wa1,
             unsigned short* __restrict__ W1p, unsigned short* __restrict__ W2p,
             unsigned short* __restrict__ Wa1p)
{
    int t = blockIdx.x * 256 + threadIdx.x;
    const float* src; unsigned short* dst; int idx;
    if (t < 4096)      { src = W1;  dst = W1p;  idx = t; }
    else if (t < 6144) { src = W2;  dst = W2p;  idx = t - 4096; }
    else               { src = Wa1; dst = Wa1p; idx = t - 6144; }
    int l   = idx & 63;
    int nt  = (idx >> 6) & 7;
    int kc  = idx >> 9;
    int col = nt * 16 + (l & 15);
    int kb  = kc * 32 + (l >> 4) * 8;
    UB o;
    #pragma unroll
    for (int j = 0; j < 8; ++j) o.u[j] = f2bf(src[(size_t)(kb + j) * H_ + col]);
    *(bf16x8*)(dst + (size_t)idx * 8) = o.v;
}

// LN(+bias) + ReLU on MFMA C/D-layout accumulators, store bf16 to htile.
// C/D layout (16x16x32): col = lane&15, row = (lane>>4)*4 + reg  [m89/m91].
// If h2p != nullptr, also keep the post-LN bf16 values packed in registers:
//   h2p[(m*8+nt)*2 + (r>>1)] = us(r even) | us(r odd)<<16
__device__ __forceinline__ void ln_relu_store(
    f32x4 (&acc)[2][8],
    const float* __restrict__ bb, const float* __restrict__ gg, const float* __restrict__ ee,
    unsigned short* __restrict__ htile, int wrow0, int n16, int kq,
    unsigned* h2p)
{
    float bc[8], gc[8], ec[8];
    #pragma unroll
    for (int nt = 0; nt < 8; ++nt) {
        int col = nt * 16 + n16;
        bc[nt] = bb[col]; gc[nt] = gg[col]; ec[nt] = ee[col];
    }
    #pragma unroll
    for (int m = 0; m < 2; ++m) {
        #pragma unroll
        for (int r = 0; r < 4; ++r) {
            float v[8];
            float s = 0.f, s2 = 0.f;
            #pragma unroll
            for (int nt = 0; nt < 8; ++nt) {
                float t = acc[m][nt][r] + bc[nt];
                v[nt] = t; s += t; s2 = fmaf(t, t, s2);
            }
            #pragma unroll
            for (int o = 1; o <= 8; o <<= 1) {
                s  += __shfl_xor(s,  o);
                s2 += __shfl_xor(s2, o);
            }
            float mu  = s * (1.f / H_);
            float var = s2 * (1.f / H_) - mu * mu;
            float rs  = rsqrtf(var + EPS_);
            int row = wrow0 + m * 16 + kq * 4 + r;
            #pragma unroll
            for (int nt = 0; nt < 8; ++nt) {
                float h = fmaxf(fmaf((v[nt] - mu) * rs, gc[nt], ec[nt]), 0.f);
                unsigned short us = f2bf(h);
                htile[row * HSTR + nt * 16 + n16] = us;
                if (h2p) {
                    unsigned& pk = h2p[(m * 8 + nt) * 2 + (r >> 1)];
                    if ((r & 1) == 0) pk = us;
                    else              pk |= ((unsigned)us) << 16;
                }
            }
        }
    }
}

// ---------------------------------------------------------------------------
// k1: per 128-row block, fully fused:
//   h1 = relu(LN(x@W1+b1)); h2 = relu(LN(h1@W2+b2));
//   w  = exp((tanh(h2@Wa1+ba1)@Wa2 + ba2)/tau)   (|score|<=11.4 -> exp<=e^38, fp32-safe)
//   partials per bag slot: Z = sum w, pooled[j] = sum w*h2[:,j]  (from registers)
// A frags: lane holds A[m=lane&15][k=(lane>>4)*8+j] (m120).
// Layer-1 x loads are double-buffered in registers (prefetch kc+1 during kc).
// ---------------------------------------------------------------------------
__global__ __launch_bounds__(256, 4)
void k1_mfma(const float* __restrict__ x,
             const unsigned short* __restrict__ W1p,
             const unsigned short* __restrict__ W2p,
             const unsigned short* __restrict__ Wa1p,
             const float* __restrict__ b1, const float* __restrict__ g1, const float* __restrict__ be1,
             const float* __restrict__ b2, const float* __restrict__ g2, const float* __restrict__ be2,
             const float* __restrict__ ba1, const float* __restrict__ Wa2, const float* __restrict__ ba2,
             float* __restrict__ Zarr, float* __restrict__ Pool)
{
    __shared__ __align__(16) unsigned short htile[RB * HSTR];   // 34816 B
    __shared__ float parr[4][2][132];                           // 4224 B

    const int tid   = threadIdx.x;
    const int w     = tid >> 6;
    const int l     = tid & 63;
    const int n16   = l & 15;
    const int kq    = l >> 4;
    const int base  = blockIdx.x * RB;
    const int wrow0 = w * 32;

    f32x4 acc[2][8];

    // ================= layer 1: x(256) @ W1 -> 128, A prefetched from global =====
    #pragma unroll
    for (int m = 0; m < 2; ++m)
        #pragma unroll
        for (int nt = 0; nt < 8; ++nt) acc[m][nt] = f32x4{0.f, 0.f, 0.f, 0.f};

    const float* xrow0 = x + (size_t)(base + wrow0 + n16) * D_ + kq * 8;
    F8 xb[2][2];                                  // [buf][m]
    #pragma unroll
    for (int m = 0; m < 2; ++m) {
        const float* xp = xrow0 + m * 16 * D_;
        xb[0][m].f4[0] = *(const float4*)xp;
        xb[0][m].f4[1] = *(const float4*)(xp + 4);
    }
    #pragma unroll
    for (int kc = 0; kc < 8; ++kc) {
        const int cur = kc & 1;
        if (kc < 7) {
            #pragma unroll
            for (int m = 0; m < 2; ++m) {
                const float* xp = xrow0 + m * 16 * D_ + (kc + 1) * 32;
                xb[cur ^ 1][m].f4[0] = *(const float4*)xp;
                xb[cur ^ 1][m].f4[1] = *(const float4*)(xp + 4);
            }
        }
        UB a[2];
        #pragma unroll
        for (int m = 0; m < 2; ++m)
            #pragma unroll
            for (int jj = 0; jj < 8; ++jj) a[m].u[jj] = f2bf(xb[cur][m].f[jj]);
        const bf16x8* bp = (const bf16x8*)W1p + (size_t)kc * 512 + l;
        #pragma unroll
        for (int nt = 0; nt < 8; ++nt) {
            bf16x8 bv = bp[nt * 64];
            acc[0][nt] = __builtin_amdgcn_mfma_f32_16x16x32_bf16(a[0].v, bv, acc[0][nt], 0, 0, 0);
            acc[1][nt] = __builtin_amdgcn_mfma_f32_16x16x32_bf16(a[1].v, bv, acc[1][nt], 0, 0, 0);
        }
    }
    ln_relu_store(acc, b1, g1, be1, htile, wrow0, n16, kq, nullptr);

    // ================= layer 2: h1(128) @ W2 -> 128, A from htile ================
    #pragma unroll
    for (int m = 0; m < 2; ++m)
        #pragma unroll
        for (int nt = 0; nt < 8; ++nt) acc[m][nt] = f32x4{0.f, 0.f, 0.f, 0.f};

    #pragma unroll
    for (int kc = 0; kc < 4; ++kc) {
        bf16x8 a[2];
        #pragma unroll
        for (int m = 0; m < 2; ++m)
            a[m] = *(const bf16x8*)&htile[(wrow0 + m * 16 + n16) * HSTR + kc * 32 + kq * 8];
        const bf16x8* bp = (const bf16x8*)W2p + (size_t)kc * 512 + l;
        #pragma unroll
        for (int nt = 0; nt < 8; ++nt) {
            bf16x8 bv = bp[nt * 64];
            acc[0][nt] = __builtin_amdgcn_mfma_f32_16x16x32_bf16(a[0], bv, acc[0][nt], 0, 0, 0);
            acc[1][nt] = __builtin_amdgcn_mfma_f32_16x16x32_bf16(a[1], bv, acc[1][nt], 0, 0, 0);
        }
    }
    unsigned h2p[32];                             // packed bf16 h2, 2x8x(4 halves)
    ln_relu_store(acc, b2, g2, be2, htile, wrow0, n16, kq, h2p);  // overwrites h1 (wave-private rows)

    // ================= attention: tanh(h2 @ Wa1 + ba1) . Wa2 + ba2 ===============
    #pragma unroll
    for (int m = 0; m < 2; ++m)
        #pragma unroll
        for (int nt = 0; nt < 8; ++nt) acc[m][nt] = f32x4{0.f, 0.f, 0.f, 0.f};

    #pragma unroll
    for (int kc = 0; kc < 4; ++kc) {
        bf16x8 a[2];
        #pragma unroll
        for (int m = 0; m < 2; ++m)
            a[m] = *(const bf16x8*)&htile[(wrow0 + m * 16 + n16) * HSTR + kc * 32 + kq * 8];
        const bf16x8* bp = (const bf16x8*)Wa1p + (size_t)kc * 512 + l;
        #pragma unroll
        for (int nt = 0; nt < 8; ++nt) {
            bf16x8 bv = bp[nt * 64];
            acc[0][nt] = __builtin_amdgcn_mfma_f32_16x16x32_bf16(a[0], bv, acc[0][nt], 0, 0, 0);
            acc[1][nt] = __builtin_amdgcn_mfma_f32_16x16x32_bf16(a[1], bv, acc[1][nt], 0, 0, 0);
        }
    }

    float pmr[2][4];                              // score/tau per (m,r) row (all lanes)
    {
        float bc[8], wc[8];
        #pragma unroll
        for (int nt = 0; nt < 8; ++nt) {
            int col = nt * 16 + n16;
            bc[nt] = ba1[col]; wc[nt] = Wa2[col];
        }
        const float ba2s = ba2[0];
        #pragma unroll
        for (int m = 0; m < 2; ++m) {
            #pragma unroll
            for (int r = 0; r < 4; ++r) {
                float p = 0.f;
                #pragma unroll
                for (int nt = 0; nt < 8; ++nt)
                    p = fmaf(fast_tanh(acc[m][nt][r] + bc[nt]), wc[nt], p);
                #pragma unroll
                for (int o = 1; o <= 8; o <<= 1) p += __shfl_xor(p, o);
                pmr[m][r] = (p + ba2s) * INV_TAU;
            }
        }
    }

    // ================= register pooling: Z + pooled per bag slot =================
    const int bag0 = base / N_;
    int rsplit = (bag0 + 1) * N_ - base;          // rows < rsplit -> slot 0; else slot 1

    float pool[2][8];
    float zz[2] = {0.f, 0.f};
    #pragma unroll
    for (int s = 0; s < 2; ++s)
        #pragma unroll
        for (int nt = 0; nt < 8; ++nt) pool[s][nt] = 0.f;

    if (rsplit >= RB) {                           // fast path (block-uniform branch)
        #pragma unroll
        for (int m = 0; m < 2; ++m)
            #pragma unroll
            for (int r = 0; r < 4; ++r) {
                float we = __expf(pmr[m][r]);
                zz[0] += we;
                #pragma unroll
                for (int nt = 0; nt < 8; ++nt) {
                    unsigned pk = h2p[(m * 8 + nt) * 2 + (r >> 1)];
                    float h = __uint_as_float((r & 1) ? (pk & 0xFFFF0000u) : (pk << 16));
                    pool[0][nt] = fmaf(we, h, pool[0][nt]);
                }
            }
    } else {                                      // straddling block (7 of 3125)
        #pragma unroll
        for (int m = 0; m < 2; ++m)
            #pragma unroll
            for (int r = 0; r < 4; ++r) {
                float we = __expf(pmr[m][r]);
                int row = wrow0 + m * 16 + kq * 4 + r;
                float w0 = (row < rsplit) ? we : 0.f;
                float w1 = we - w0;
                zz[0] += w0; zz[1] += w1;
                #pragma unroll
                for (int nt = 0; nt < 8; ++nt) {
                    unsigned pk = h2p[(m * 8 + nt) * 2 + (r >> 1)];
                    float h = __uint_as_float((r & 1) ? (pk & 0xFFFF0000u) : (pk << 16));
                    pool[0][nt] = fmaf(w0, h, pool[0][nt]);
                    pool[1][nt] = fmaf(w1, h, pool[1][nt]);
                }
            }
    }
    #pragma unroll
    for (int s = 0; s < 2; ++s) {
        zz[s] += __shfl_xor(zz[s], 16);
        zz[s] += __shfl_xor(zz[s], 32);
        #pragma unroll
        for (int nt = 0; nt < 8; ++nt) {
            pool[s][nt] += __shfl_xor(pool[s][nt], 16);
            pool[s][nt] += __shfl_xor(pool[s][nt], 32);
        }
    }
    if (kq == 0) {
        #pragma unroll
        for (int s = 0; s < 2; ++s)
            #pragma unroll
            for (int nt = 0; nt < 8; ++nt)
                parr[w][s][nt * 16 + n16] = pool[s][nt];
    }
    if (l == 0) {
        parr[w][0][128] = zz[0];
        parr[w][1][128] = zz[1];
    }
    __syncthreads();

    {
        const int slot = tid >> 7, col = tid & 127;
        float s4 = parr[0][slot][col] + parr[1][slot][col]
                 + parr[2][slot][col] + parr[3][slot][col];
        Pool[((size_t)blockIdx.x * 2 + slot) * H_ + col] = s4;
        if (col == 0)
            Zarr[blockIdx.x * 2 + slot] = parr[0][slot][128] + parr[1][slot][128]
                                        + parr[2][slot][128] + parr[3][slot][128];
    }
}

// ---------------------------------------------------------------------------
// k2: per bag, merge block partials (4-way chunked) + both heads. 8 x 512.
// ---------------------------------------------------------------------------
__global__ __launch_bounds__(512)
void k2_combine(const float* __restrict__ Zarr, const float* __restrict__ Pool,
                const float* __restrict__ Wc1, const float* __restrict__ bc1,
                const float* __restrict__ Wc2, const float* __restrict__ bc2,
                const float* __restrict__ Ws1, const float* __restrict__ bs1,
                const float* __restrict__ Ws2, const float* __restrict__ bs2,
                float* __restrict__ out)
{
    const int b   = blockIdx.x;
    const int tid = threadIdx.x;
    const int j   = tid & 127, ch = tid >> 7;
    __shared__ float pacc[4][128];
    __shared__ float zacc[4];
    __shared__ float bl[H_], ul[H_], vl[64];

    const int blk0 = (b * N_) / RB;
    const int blk1 = ((b + 1) * N_ - 1) / RB;
    float ps = 0.f, zs = 0.f;
    for (int blk = blk0 + ch; blk <= blk1; blk += 4) {
        int bag0 = (blk * RB) / N_;
        if (bag0 == b)     { ps += Pool[((size_t)blk * 2 + 0) * H_ + j]; zs += Zarr[blk * 2 + 0]; }
        if (bag0 + 1 == b) { ps += Pool[((size_t)blk * 2 + 1) * H_ + j]; zs += Zarr[blk * 2 + 1]; }
    }
    pacc[ch][j] = ps;
    if (j == 0) zacc[ch] = zs;
    __syncthreads();

    if (tid < 128) {
        float p = pacc[0][j] + pacc[1][j] + pacc[2][j] + pacc[3][j];
        float z = zacc[0] + zacc[1] + zacc[2] + zacc[3];
        bl[j] = p / z;
    }
    __syncthreads();

    if (tid < 128) {
        float a = bc1[j];
        for (int k = 0; k < H_; ++k) a = fmaf(bl[k], Wc1[k * H_ + j], a);
        ul[j] = fmaxf(a, 0.f);
        if (j < 64) {
            float a2 = bs1[j];
            for (int k = 0; k < H_; ++k) a2 = fmaf(bl[k], Ws1[k * 64 + j], a2);
            vl[j] = fmaxf(a2, 0.f);
        }
    }
    __syncthreads();

    if (tid < 2) {
        float a3 = bc2[tid];
        for (int k = 0; k < H_; ++k) a3 = fmaf(ul[k], Wc2[k * 2 + tid], a3);
        out[b * 2 + tid] = a3;
    }
    if (tid == 2) {
        float a4 = bs2[0];
        for (int k = 0; k < 64; ++k) a4 = fmaf(vl[k], Ws2[k], a4);
        out[16 + b] = a4;
    }
}

extern "C" void kernel_launch(void* const* d_in, const int* in_sizes, int n_in,
                              void* d_out, int out_size, void* d_ws, size_t ws_size,
                              hipStream_t stream)
{
    (void)in_sizes; (void)n_in; (void)out_size; (void)ws_size;

    const float* x   = (const float*)d_in[0];
    const float* W1  = (const float*)d_in[1];
    const float* b1  = (const float*)d_in[2];
    const float* g1  = (const float*)d_in[3];
    const float* be1 = (const float*)d_in[4];
    const float* W2  = (const float*)d_in[5];
    const float* b2  = (const float*)d_in[6];
    const float* g2  = (const float*)d_in[7];
    const float* be2 = (const float*)d_in[8];
    const float* Wa1 = (const float*)d_in[9];
    const float* ba1 = (const float*)d_in[10];
    const float* Wa2 = (const float*)d_in[11];
    const float* ba2 = (const float*)d_in[12];
    const float* Wc1 = (const float*)d_in[13];
    const float* bc1 = (const float*)d_in[14];
    const float* Wc2 = (const float*)d_in[15];
    const float* bc2 = (const float*)d_in[16];
    const float* Ws1 = (const float*)d_in[17];
    const float* bs1 = (const float*)d_in[18];
    const float* Ws2 = (const float*)d_in[19];
    const float* bs2 = (const float*)d_in[20];

    // workspace layout (16B-aligned segments)
    char* ws = (char*)d_ws;
    float* Zarr          = (float*)ws;                       // 25,000 B
    float* Pool          = (float*)(ws + 25088);             // 3,200,000 B
    unsigned short* W1p  = (unsigned short*)(ws + 3225088);  // 64 KB
    unsigned short* W2p  = (unsigned short*)(ws + 3290624);  // 32 KB
    unsigned short* Wa1p = (unsigned short*)(ws + 3323392);  // 32 KB

    k0_pack<<<32, 256, 0, stream>>>(W1, W2, Wa1, W1p, W2p, Wa1p);
    k1_mfma<<<NBLK, 256, 0, stream>>>(x, W1p, W2p, Wa1p,
                                      b1, g1, be1, b2, g2, be2,
                                      ba1, Wa2, ba2, Zarr, Pool);
    k2_combine<<<B_, 512, 0, stream>>>(Zarr, Pool, Wc1, bc1, Wc2, bc2,
                                       Ws1, bs1, Ws2, bs2, (float*)d_out);
}